// Round 1
// baseline (316.673 us; speedup 1.0000x reference)
//
#include <hip/hip_runtime.h>
#include <hip/hip_bf16.h>

// Problem constants (from reference setup_inputs):
// B=32, C=256, H=36, W=64, n=4096.  P = H*W = 2304.  NCOL = B*C = 8192.
#define P_HW   2304
#define NG     4096
#define NCOL   8192
#define KDIM   P_HW

typedef __bf16 bf16x8 __attribute__((ext_vector_type(8)));
typedef float  f32x4  __attribute__((ext_vector_type(4)));

__device__ __forceinline__ unsigned short f2bf(float f) {
    union { float f; unsigned int u; } x; x.f = f;
    unsigned int r = x.u + 0x7FFFu + ((x.u >> 16) & 1u);   // RNE
    return (unsigned short)(r >> 16);
}

// ---------------------------------------------------------------------------
// Kernel 1: Gaussian masks G[n][p] in bf16, row-major (K-contiguous for GEMM A)
// ---------------------------------------------------------------------------
__global__ void mask_kernel(const float* __restrict__ mu,
                            const float* __restrict__ logsx,
                            const float* __restrict__ logsy,
                            const float* __restrict__ rho,
                            unsigned short* __restrict__ G) {
    const int n = blockIdx.x;
    const float mux = mu[2 * n], muy = mu[2 * n + 1];
    const float sx = __expf(logsx[n]) + 1e-6f;
    const float sy = __expf(logsy[n]) + 1e-6f;
    const float r  = tanhf(rho[n]);
    const float inv_den = 1.0f / (2.0f * (1.0f - r * r + 1e-6f));
    const float isx = 1.0f / sx, isy = 1.0f / sy;
    for (int p = threadIdx.x; p < P_HW; p += 256) {
        const int h = p >> 6, w = p & 63;              // W = 64
        const float X = -1.0f + (float)w * (2.0f / 63.0f);
        const float Y = -1.0f + (float)h * (2.0f / 35.0f);
        const float xc = (X - mux) * isx;
        const float yc = (Y - muy) * isy;
        const float A = xc * xc + yc * yc - 2.0f * r * xc * yc;
        G[(size_t)n * P_HW + p] = f2bf(__expf(-A * inv_den));
    }
}

// ---------------------------------------------------------------------------
// Kernel 2: cast feat fp32 -> bf16, layout [B*C][P] (already K-contiguous)
// ---------------------------------------------------------------------------
__global__ void cast_feat(const float* __restrict__ feat,
                          unsigned short* __restrict__ F) {
    const size_t i = ((size_t)blockIdx.x * 256 + threadIdx.x) * 8;
    const float4 v0 = *(const float4*)(feat + i);
    const float4 v1 = *(const float4*)(feat + i + 4);
    union { unsigned short s[8]; uint4 q; } o;
    o.s[0] = f2bf(v0.x); o.s[1] = f2bf(v0.y); o.s[2] = f2bf(v0.z); o.s[3] = f2bf(v0.w);
    o.s[4] = f2bf(v1.x); o.s[5] = f2bf(v1.y); o.s[6] = f2bf(v1.z); o.s[7] = f2bf(v1.w);
    *(uint4*)(F + i) = o.q;
}

// ---------------------------------------------------------------------------
// Kernel 3: C = G(4096 x K) * Feat^T(8192 x K)^T with fused weight-dot epilogue
// m97 structure: 128x128 tile, BK=32, global_load_lds(16B), 16x16x32 bf16 MFMA
// ---------------------------------------------------------------------------
__device__ __forceinline__ void async16(const void* g, void* l) {
    __builtin_amdgcn_global_load_lds(
        (__attribute__((address_space(1))) void*)(unsigned long long)g,
        (__attribute__((address_space(3))) void*)(unsigned int)(unsigned long long)l,
        16, 0, 0);
}

__global__ __launch_bounds__(256) void gemm_fused(
    const unsigned short* __restrict__ G,   // [NG][K] bf16
    const unsigned short* __restrict__ F,   // [NCOL][K] bf16
    const float* __restrict__ weight,       // [NG][256] fp32
    float* __restrict__ out)                // [32][NG] fp32 (pre-zeroed)
{
    __shared__ __align__(16) unsigned short ldsA[128 * 32];
    __shared__ __align__(16) unsigned short ldsB[128 * 32];

    const int tid  = threadIdx.x;
    const int lane = tid & 63;
    const int wave = tid >> 6;
    const int waveM = wave >> 1, waveN = wave & 1;
    const int quad = lane >> 4, m = lane & 15;

    const int rowBase = blockIdx.y * 128;   // over NG (gaussians)
    const int colBase = blockIdx.x * 128;   // over NCOL (b*256+c)

    // staging: 512 chunks of 16B per (A|B) tile pair -> 2 issues each
    const int idx0 = tid, idx1 = tid + 256;
    const int r0 = idx0 >> 2, c0 = (idx0 & 3) * 8;
    const int r1 = idx1 >> 2, c1 = (idx1 & 3) * 8;

    const unsigned short* Ag0 = G + (size_t)(rowBase + r0) * KDIM + c0;
    const unsigned short* Ag1 = G + (size_t)(rowBase + r1) * KDIM + c1;
    const unsigned short* Bg0 = F + (size_t)(colBase + r0) * KDIM + c0;
    const unsigned short* Bg1 = F + (size_t)(colBase + r1) * KDIM + c1;

    f32x4 acc[4][4];
#pragma unroll
    for (int i = 0; i < 4; ++i)
#pragma unroll
        for (int j = 0; j < 4; ++j)
            acc[i][j] = (f32x4){0.f, 0.f, 0.f, 0.f};

    for (int k0 = 0; k0 < KDIM; k0 += 32) {
        async16(Ag0 + k0, &ldsA[idx0 * 8]);
        async16(Ag1 + k0, &ldsA[idx1 * 8]);
        async16(Bg0 + k0, &ldsB[idx0 * 8]);
        async16(Bg1 + k0, &ldsB[idx1 * 8]);
        __syncthreads();

        bf16x8 a[4], b[4];
#pragma unroll
        for (int i = 0; i < 4; ++i)
            a[i] = *(const bf16x8*)&ldsA[(waveM * 64 + i * 16 + m) * 32 + quad * 8];
#pragma unroll
        for (int j = 0; j < 4; ++j)
            b[j] = *(const bf16x8*)&ldsB[(waveN * 64 + j * 16 + m) * 32 + quad * 8];

#pragma unroll
        for (int i = 0; i < 4; ++i)
#pragma unroll
            for (int j = 0; j < 4; ++j)
                acc[i][j] = __builtin_amdgcn_mfma_f32_16x16x32_bf16(a[i], b[j], acc[i][j], 0, 0, 0);
        __syncthreads();
    }

    // Epilogue: out[b][n] += sum_c pooled[n][b*256+c] * weight[n][c]
    // This block's 128 cols lie inside one batch b; cols-within-C base:
    const int bidx  = colBase >> 8;
    const int cwave = (colBase & 255) + waveN * 64;   // + j*16 + m
#pragma unroll
    for (int i = 0; i < 4; ++i) {
        const int nrow = rowBase + waveM * 64 + i * 16 + quad * 4;  // + reg
#pragma unroll
        for (int reg = 0; reg < 4; ++reg) {
            const float* wrow = weight + (size_t)(nrow + reg) * 256 + cwave + m;
            float s = acc[i][0][reg] * wrow[0]
                    + acc[i][1][reg] * wrow[16]
                    + acc[i][2][reg] * wrow[32]
                    + acc[i][3][reg] * wrow[48];
            // reduce over the 16 lanes of this quad (same n-row, different cols)
            s += __shfl_xor(s, 1);
            s += __shfl_xor(s, 2);
            s += __shfl_xor(s, 4);
            s += __shfl_xor(s, 8);
            if (m == 0)
                atomicAdd(out + (size_t)bidx * NG + nrow + reg, s);
        }
    }
}

// ---------------------------------------------------------------------------
extern "C" void kernel_launch(void* const* d_in, const int* in_sizes, int n_in,
                              void* d_out, int out_size, void* d_ws, size_t ws_size,
                              hipStream_t stream) {
    const float* feat   = (const float*)d_in[0];
    const float* mu     = (const float*)d_in[1];
    const float* logsx  = (const float*)d_in[2];
    const float* logsy  = (const float*)d_in[3];
    const float* rho    = (const float*)d_in[4];
    const float* weight = (const float*)d_in[5];
    float* out = (float*)d_out;

    unsigned short* Gbuf = (unsigned short*)d_ws;                  // 4096*2304*2 B
    unsigned short* Fbuf = Gbuf + (size_t)NG * P_HW;               // 8192*2304*2 B

    hipMemsetAsync(out, 0, (size_t)32 * NG * sizeof(float), stream);

    hipLaunchKernelGGL(mask_kernel, dim3(NG), dim3(256), 0, stream,
                       mu, logsx, logsy, rho, Gbuf);

    // 32*256*2304 / 8 elems per thread / 256 threads = 9216 blocks
    hipLaunchKernelGGL(cast_feat, dim3(9216), dim3(256), 0, stream, feat, Fbuf);

    hipLaunchKernelGGL(gemm_fused, dim3(NCOL / 128, NG / 128), dim3(256), 0, stream,
                       Gbuf, Fbuf, weight, out);
}

// Round 2
// 312.783 us; speedup vs baseline: 1.0124x; 1.0124x over previous
//
#include <hip/hip_runtime.h>
#include <hip/hip_bf16.h>

// B=32, C=256, H=36, W=64, n=4096.  P = H*W = 2304.  NCOL = B*C = 8192.
#define P_HW   2304
#define NG     4096
#define NCOL   8192
#define KDIM   P_HW

typedef __bf16 bf16x8 __attribute__((ext_vector_type(8)));
typedef float  f32x4  __attribute__((ext_vector_type(4)));

__device__ __forceinline__ unsigned short f2bf(float f) {
    union { float f; unsigned int u; } x; x.f = f;
    unsigned int r = x.u + 0x7FFFu + ((x.u >> 16) & 1u);   // RNE
    return (unsigned short)(r >> 16);
}

// ---------------------------------------------------------------------------
// Kernel 1: Gaussian masks G[n][p] in bf16, row-major. 8 px/thread, uint4 store
// ---------------------------------------------------------------------------
__global__ void mask_kernel(const float* __restrict__ mu,
                            const float* __restrict__ logsx,
                            const float* __restrict__ logsy,
                            const float* __restrict__ rho,
                            unsigned short* __restrict__ G) {
    const int n = blockIdx.x;
    const float mux = mu[2 * n], muy = mu[2 * n + 1];
    const float sx = __expf(logsx[n]) + 1e-6f;
    const float sy = __expf(logsy[n]) + 1e-6f;
    const float r  = tanhf(rho[n]);
    const float inv_den = 1.0f / (2.0f * (1.0f - r * r + 1e-6f));
    const float isx = 1.0f / sx, isy = 1.0f / sy;
    for (int base = threadIdx.x * 8; base < P_HW; base += 2048) {
        const int h = base >> 6, w0 = base & 63;          // 8 px stay in one row
        const float Y  = -1.0f + (float)h * (2.0f / 35.0f);
        const float yc = (Y - muy) * isy;
        union { unsigned short s[8]; uint4 q; } o;
#pragma unroll
        for (int j = 0; j < 8; ++j) {
            const float X  = -1.0f + (float)(w0 + j) * (2.0f / 63.0f);
            const float xc = (X - mux) * isx;
            const float A  = xc * xc + yc * yc - 2.0f * r * xc * yc;
            o.s[j] = f2bf(__expf(-A * inv_den));
        }
        *(uint4*)&G[(size_t)n * P_HW + base] = o.q;
    }
}

// ---------------------------------------------------------------------------
// Kernel 2: cast feat fp32 -> bf16, layout [B*C][P]
// ---------------------------------------------------------------------------
__global__ void cast_feat(const float* __restrict__ feat,
                          unsigned short* __restrict__ F) {
    const size_t i = ((size_t)blockIdx.x * 256 + threadIdx.x) * 8;
    const float4 v0 = *(const float4*)(feat + i);
    const float4 v1 = *(const float4*)(feat + i + 4);
    union { unsigned short s[8]; uint4 q; } o;
    o.s[0] = f2bf(v0.x); o.s[1] = f2bf(v0.y); o.s[2] = f2bf(v0.z); o.s[3] = f2bf(v0.w);
    o.s[4] = f2bf(v1.x); o.s[5] = f2bf(v1.y); o.s[6] = f2bf(v1.z); o.s[7] = f2bf(v1.w);
    *(uint4*)(F + i) = o.q;
}

// ---------------------------------------------------------------------------
// Kernel 3: GEMM 128x128 tile, BK=64, XOR-swizzled LDS (conflict-free b128),
// global_load_lds(16B) staging, 16x16x32 bf16 MFMA, fused weight-dot epilogue
// ---------------------------------------------------------------------------
__device__ __forceinline__ void async16(const void* g, void* l) {
    __builtin_amdgcn_global_load_lds(
        (__attribute__((address_space(1))) void*)(unsigned long long)g,
        (__attribute__((address_space(3))) void*)(unsigned int)(unsigned long long)l,
        16, 0, 0);
}

__global__ __launch_bounds__(256) void gemm_fused(
    const unsigned short* __restrict__ G,   // [NG][K] bf16
    const unsigned short* __restrict__ F,   // [NCOL][K] bf16
    const float* __restrict__ weight,       // [NG][256] fp32
    float* __restrict__ out)                // [32][NG] fp32 (pre-zeroed)
{
    // 128 rows x 64 k-elems per tile; row stride 128B; chunk = 16B (8 bf16)
    // LDS slot (r, cp) holds global chunk c = cp ^ (r&7)  [XOR swizzle]
    __shared__ __align__(16) unsigned short ldsA[128 * 64];
    __shared__ __align__(16) unsigned short ldsB[128 * 64];

    const int tid  = threadIdx.x;
    const int lane = tid & 63;
    const int wave = tid >> 6;
    const int waveM = wave >> 1, waveN = wave & 1;
    const int quad = lane >> 4, m = lane & 15;

    const int rowBase = blockIdx.y * 128;   // over NG
    const int colBase = blockIdx.x * 128;   // over NCOL (b*256+c)

    // staging: 1024 slots of 16B per tile -> 4 issues/thread per tile
    const unsigned short* Aptr[4];
    const unsigned short* Bptr[4];
    int ldsOff[4];
#pragma unroll
    for (int i = 0; i < 4; ++i) {
        const int s  = i * 256 + tid;
        const int r  = s >> 3;
        const int cp = s & 7;
        const int c  = cp ^ (r & 7);           // swizzled source chunk
        Aptr[i] = G + (size_t)(rowBase + r) * KDIM + c * 8;
        Bptr[i] = F + (size_t)(colBase + r) * KDIM + c * 8;
        ldsOff[i] = s * 8;                     // elems
    }

    f32x4 acc[4][4];
#pragma unroll
    for (int i = 0; i < 4; ++i)
#pragma unroll
        for (int j = 0; j < 4; ++j)
            acc[i][j] = (f32x4){0.f, 0.f, 0.f, 0.f};

    for (int k0 = 0; k0 < KDIM; k0 += 64) {
#pragma unroll
        for (int i = 0; i < 4; ++i) async16(Aptr[i] + k0, &ldsA[ldsOff[i]]);
#pragma unroll
        for (int i = 0; i < 4; ++i) async16(Bptr[i] + k0, &ldsB[ldsOff[i]]);
        __syncthreads();

#pragma unroll
        for (int h = 0; h < 2; ++h) {
            bf16x8 a[4], b[4];
#pragma unroll
            for (int i = 0; i < 4; ++i) {
                const int r  = waveM * 64 + i * 16 + m;
                const int cp = (h * 4 + quad) ^ (r & 7);
                a[i] = *(const bf16x8*)&ldsA[r * 64 + cp * 8];
            }
#pragma unroll
            for (int j = 0; j < 4; ++j) {
                const int r  = waveN * 64 + j * 16 + m;
                const int cp = (h * 4 + quad) ^ (r & 7);
                b[j] = *(const bf16x8*)&ldsB[r * 64 + cp * 8];
            }
#pragma unroll
            for (int i = 0; i < 4; ++i)
#pragma unroll
                for (int j = 0; j < 4; ++j)
                    acc[i][j] = __builtin_amdgcn_mfma_f32_16x16x32_bf16(a[i], b[j], acc[i][j], 0, 0, 0);
        }
        __syncthreads();
    }

    // Epilogue: out[b][n] += sum_c pooled[n][b*256+c] * weight[n][c]
    const int bidx  = colBase >> 8;
    const int cwave = (colBase & 255) + waveN * 64;   // + j*16 + m
#pragma unroll
    for (int i = 0; i < 4; ++i) {
        const int nrow = rowBase + waveM * 64 + i * 16 + quad * 4;  // + reg
#pragma unroll
        for (int reg = 0; reg < 4; ++reg) {
            const float* wrow = weight + (size_t)(nrow + reg) * 256 + cwave + m;
            float s = acc[i][0][reg] * wrow[0]
                    + acc[i][1][reg] * wrow[16]
                    + acc[i][2][reg] * wrow[32]
                    + acc[i][3][reg] * wrow[48];
            s += __shfl_xor(s, 1);
            s += __shfl_xor(s, 2);
            s += __shfl_xor(s, 4);
            s += __shfl_xor(s, 8);
            if (m == 0)
                atomicAdd(out + (size_t)bidx * NG + nrow + reg, s);
        }
    }
}

// ---------------------------------------------------------------------------
extern "C" void kernel_launch(void* const* d_in, const int* in_sizes, int n_in,
                              void* d_out, int out_size, void* d_ws, size_t ws_size,
                              hipStream_t stream) {
    const float* feat   = (const float*)d_in[0];
    const float* mu     = (const float*)d_in[1];
    const float* logsx  = (const float*)d_in[2];
    const float* logsy  = (const float*)d_in[3];
    const float* rho    = (const float*)d_in[4];
    const float* weight = (const float*)d_in[5];
    float* out = (float*)d_out;

    unsigned short* Gbuf = (unsigned short*)d_ws;                  // 4096*2304*2 B
    unsigned short* Fbuf = Gbuf + (size_t)NG * P_HW;               // 8192*2304*2 B

    hipMemsetAsync(out, 0, (size_t)32 * NG * sizeof(float), stream);

    hipLaunchKernelGGL(mask_kernel, dim3(NG), dim3(256), 0, stream,
                       mu, logsx, logsy, rho, Gbuf);

    hipLaunchKernelGGL(cast_feat, dim3(9216), dim3(256), 0, stream, feat, Fbuf);

    hipLaunchKernelGGL(gemm_fused, dim3(NCOL / 128, NG / 128), dim3(256), 0, stream,
                       Gbuf, Fbuf, weight, out);
}